// Round 5
// baseline (490.668 us; speedup 1.0000x reference)
//
#include <hip/hip_runtime.h>
#include <stdint.h>

#define IN_F 2048
#define OUT_F 2048
#define MTOK 16384   // 4 * 4096 tokens

typedef __attribute__((ext_vector_type(8))) __bf16 bf16x8;
typedef __attribute__((ext_vector_type(4))) float f32x4;
typedef __attribute__((ext_vector_type(4))) unsigned short us4;
typedef __attribute__((ext_vector_type(8))) unsigned short us8;

typedef const __attribute__((address_space(1))) void g_void;
typedef __attribute__((address_space(3))) void l_void;

// 16B async global->LDS (wave-uniform LDS base + lane*16; swizzle on global src)
__device__ __forceinline__ void async16(void* lds, const void* g) {
    __builtin_amdgcn_global_load_lds((g_void*)(uintptr_t)g, (l_void*)(uintptr_t)lds, 16, 0, 0);
}

// fp32 -> bf16 round-to-nearest-even (bit-identical across all uses)
__device__ __forceinline__ unsigned short f2bf(float x) {
    union { float f; uint32_t u; } v; v.f = x;
    uint32_t r = v.u + 0x7fffu + ((v.u >> 16) & 1u);
    return (unsigned short)(r >> 16);
}

// ---------------------------------------------------------------------------
// K_perm: Bpf[o][i] = MW[o][((i&31)<<6)|(i>>5)]  (shuffle folded into columns,
// fp32, exact). One MW row per block; coalesced read -> padded LDS ->
// permuted read (2-way banks, free) -> coalesced write. ~32 MB traffic.
// ---------------------------------------------------------------------------
__global__ __launch_bounds__(256) void k_perm(
    const float* __restrict__ MW, float* __restrict__ Bpf) {
    __shared__ float buf[2112];   // 2048 + pad every 32
    const int t = threadIdx.x;
    const float* src = MW + (size_t)blockIdx.x * 2048;
    float* dst = Bpf + (size_t)blockIdx.x * 2048;
#pragma unroll
    for (int q = 0; q < 2; ++q) {
        int id4 = q * 256 + t;
        float4 v = *(const float4*)(src + id4 * 4);
        int i = id4 * 4;
        int b = i + (i >> 5);
        buf[b] = v.x; buf[b + 1] = v.y; buf[b + 2] = v.z; buf[b + 3] = v.w;
    }
    __syncthreads();
#pragma unroll
    for (int q = 0; q < 8; ++q) {
        int j = q * 256 + t;
        int i = ((j & 31) << 6) | (j >> 5);
        dst[j] = buf[i + (i >> 5)];
    }
}

// ---------------------------------------------------------------------------
// K_fold: exact fp32 weight fold (butterfly = one linear map):
//   M1[o][g*64+c]   = sum_d W1[g][c][d] * Bp[o][g*64+d]
//   B2[g2*64+d2][i] = sum_c2 W2[g2][c2][d2] * M1[g2*64+c2][i]
// Bp tile now read COALESCED from pre-permuted Bpf (R3's strided MW gather
// was ~8x over-fetch + latency-bound -> the 75us pig). Compute identical to
// R3 (verified): per-lane k-stagger on both inner loops, W2 untransposed.
// ---------------------------------------------------------------------------
#define FP 68   // padded fp32 row: 272B, 16B-aligned

__global__ __launch_bounds__(256) void k_fold(
    const float* __restrict__ s1, const float* __restrict__ s2,
    const float* __restrict__ Bpf, unsigned short* __restrict__ Bb) {
    __shared__ float B0[64 * FP];   // W1[c][d]  -> later M1t[c][o]
    __shared__ float B1[64 * FP];   // Bp[o][d]  -> later W2[c2][d2] (as loaded)
    const int t = threadIdx.x;
    const int g  = blockIdx.x & 31;
    const int rt = blockIdx.x >> 5;
    const int l = t & 15, h = t >> 4;    // h in [0,16)

    // B0[c][d] = stage1[g*64+c][d]  (coalesced float4)
#pragma unroll
    for (int q = 0; q < 4; ++q) {
        int id = q * 256 + t;            // [0,1024)
        int c = id >> 4, d4 = id & 15;
        *(float4*)&B0[c * FP + d4 * 4] =
            *(const float4*)(s1 + (size_t)(g * 64 + c) * 64 + d4 * 4);
    }
    // B1[o][d] = Bpf[rt*64+o][g*64+d]  (coalesced float4, each elem read once)
#pragma unroll
    for (int q = 0; q < 4; ++q) {
        int id = q * 256 + t;            // [0,1024)
        int o = id >> 4, d4 = id & 15;
        *(float4*)&B1[o * FP + d4 * 4] =
            *(const float4*)(Bpf + (size_t)(rt * 64 + o) * 2048 + g * 64 + d4 * 4);
    }
    __syncthreads();

    // step 3: M1t[c][o] = sum_d Bp[o][d] * W1[c][d]; thread owns c=4l..+3, o=4h..+3
    float acc[4][4];
#pragma unroll
    for (int i = 0; i < 4; ++i)
#pragma unroll
        for (int j = 0; j < 4; ++j) acc[i][j] = 0.f;
    {
        const int co = l * 4, oo = h * 4;
#pragma unroll
        for (int dc = 0; dc < 16; ++dc) {
            const int dce = (dc + l) & 15;           // lane k-stagger
            float4 bv[4], wv[4];
#pragma unroll
            for (int i = 0; i < 4; ++i) bv[i] = *(const float4*)&B1[(oo + i) * FP + dce * 4];
#pragma unroll
            for (int j = 0; j < 4; ++j) wv[j] = *(const float4*)&B0[(co + j) * FP + dce * 4];
#pragma unroll
            for (int i = 0; i < 4; ++i)
#pragma unroll
                for (int j = 0; j < 4; ++j)
                    acc[i][j] += bv[i].x * wv[j].x + bv[i].y * wv[j].y
                               + bv[i].z * wv[j].z + bv[i].w * wv[j].w;
        }
    }
    __syncthreads();   // all reads of B0(W1)/B1(Bp) done

    // write M1t[c][o] into B0 (float4 along o); load W2 into B1 as-is
    {
        const int co = l * 4, oo = h * 4;
#pragma unroll
        for (int j = 0; j < 4; ++j) {
            float4 v; v.x = acc[0][j]; v.y = acc[1][j]; v.z = acc[2][j]; v.w = acc[3][j];
            *(float4*)&B0[(co + j) * FP + oo] = v;
        }
    }
#pragma unroll
    for (int q = 0; q < 4; ++q) {
        int id = q * 256 + t;            // [0,1024)
        int c2 = id >> 4, d4 = id & 15;
        *(float4*)&B1[c2 * FP + d4 * 4] =
            *(const float4*)(s2 + (size_t)(rt * 64 + c2) * 64 + d4 * 4);
    }
    __syncthreads();

    // step 5: B2[d2][c] = sum_o W2[o][d2] * M1t[c][o]; thread owns d2=4l..+3, c=4h..+3
    {
        const int d2o = l * 4, cco = h * 4;
#pragma unroll
        for (int i = 0; i < 4; ++i)
#pragma unroll
            for (int j = 0; j < 4; ++j) acc[i][j] = 0.f;
#pragma unroll
        for (int kc = 0; kc < 16; ++kc) {
            const int kce = (kc + l) & 15;           // lane k-stagger
            float4 wv4[4], mv[4];
#pragma unroll
            for (int s = 0; s < 4; ++s) wv4[s] = *(const float4*)&B1[(kce * 4 + s) * FP + d2o];
#pragma unroll
            for (int j = 0; j < 4; ++j) mv[j] = *(const float4*)&B0[(cco + j) * FP + kce * 4];
#pragma unroll
            for (int i = 0; i < 4; ++i)
#pragma unroll
                for (int j = 0; j < 4; ++j)
                    acc[i][j] += wv4[0][i] * mv[j].x + wv4[1][i] * mv[j].y
                               + wv4[2][i] * mv[j].z + wv4[3][i] * mv[j].w;
        }
#pragma unroll
        for (int i = 0; i < 4; ++i) {
            us4 o;
            o[0] = f2bf(acc[i][0]); o[1] = f2bf(acc[i][1]);
            o[2] = f2bf(acc[i][2]); o[3] = f2bf(acc[i][3]);
            *(us4*)(Bb + (size_t)(rt * 64 + d2o + i) * 2048 + g * 64 + cco) = o;
        }
    }
}

// ---------------------------------------------------------------------------
// K1: the single GEMM, fp32 X in (convert fused into A-staging).
// C[m][o2] = sum_i bf16(X[m][i]) * Bb[o2][i].
// B side: async global->LDS with pre-swizzled source (unchanged, proven).
// A side: reg-staged — load 8 fp32 at the NATURAL chunk, f2bf (identical
// rounding to the old k_convert), one ds_write_b128 to the SWIZZLED slot.
// Invariant preserved: LDS[r][s] = global chunk s^(r&7), so the read side
// and MFMA phase are byte-identical to R3. Chunked XCD remap kept
// (FETCH 283->214 MB verified in R3).
// ---------------------------------------------------------------------------
__global__ __launch_bounds__(256, 2) void k_gemm(
    const float* __restrict__ X, const unsigned short* __restrict__ B,
    float* __restrict__ C) {
    __shared__ unsigned short smem[16384];   // As 16KB | Bs 16KB
    unsigned short* As = smem;
    unsigned short* Bs = smem + 8192;
    const int t = threadIdx.x;
    const int lane = t & 63, wave = t >> 6;
    const int quad = lane >> 4, l16 = lane & 15;
    const int mw = wave & 1, nw = wave >> 1;
    const int orig = blockIdx.y * 128 + blockIdx.x;
    const int lin = (orig & 7) * 256 + (orig >> 3);   // chunked XCD swizzle
    const int m0 = (lin >> 4) * 128;
    const int n0 = (lin & 15) * 128;
    const int rr = t >> 3, chunk = t & 7;      // 32 rows x 8 16B-chunks per issue
    const int gsw = (chunk ^ (rr & 7)) * 8;    // swizzled chunk offset (shorts)
    const int lsw = l16 & 7;                   // read-side swizzle key

    f32x4 acc[4][4];
#pragma unroll
    for (int i = 0; i < 4; ++i)
#pragma unroll
        for (int j = 0; j < 4; ++j) acc[i][j] = (f32x4)0.f;

    for (int kb = 0; kb < IN_F; kb += 64) {
        // A loads first (start HBM fetch early); natural chunk position
        float4 a0[4], a1[4];
#pragma unroll
        for (int q = 0; q < 4; ++q) {
            const float* xp = X + (size_t)(m0 + q * 32 + rr) * IN_F + kb + chunk * 8;
            a0[q] = *(const float4*)xp;
            a1[q] = *(const float4*)(xp + 4);
        }
        // B: async global->LDS, pre-swizzled source (unchanged)
#pragma unroll
        for (int q = 0; q < 4; ++q) {
            int r = q * 32 + rr;
            async16((char*)Bs + (size_t)(q * 4096 + t * 16),
                    B + (size_t)(n0 + r) * IN_F + kb + gsw);
        }
        // A: cvt + swizzled-slot ds_write (conflict-free: 8 lanes cover one
        // full 128B row, XOR is a within-row permutation)
#pragma unroll
        for (int q = 0; q < 4; ++q) {
            us8 pk;
            pk[0] = f2bf(a0[q].x); pk[1] = f2bf(a0[q].y);
            pk[2] = f2bf(a0[q].z); pk[3] = f2bf(a0[q].w);
            pk[4] = f2bf(a1[q].x); pk[5] = f2bf(a1[q].y);
            pk[6] = f2bf(a1[q].z); pk[7] = f2bf(a1[q].w);
            *(us8*)(As + (q * 32 + rr) * 64 + gsw) = pk;
        }
        __syncthreads();
#pragma unroll
        for (int ks = 0; ks < 2; ++ks) {
            bf16x8 af[4], bfr[4];
#pragma unroll
            for (int i = 0; i < 4; ++i)
                af[i] = *(const bf16x8*)(As + (mw * 64 + i * 16 + l16) * 64
                                            + (((ks * 4 + quad) ^ lsw) * 8));
#pragma unroll
            for (int j = 0; j < 4; ++j)
                bfr[j] = *(const bf16x8*)(Bs + (nw * 64 + j * 16 + l16) * 64
                                             + (((ks * 4 + quad) ^ lsw) * 8));
#pragma unroll
            for (int i = 0; i < 4; ++i)
#pragma unroll
                for (int j = 0; j < 4; ++j)
                    acc[i][j] = __builtin_amdgcn_mfma_f32_16x16x32_bf16(af[i], bfr[j], acc[i][j], 0, 0, 0);
        }
        __syncthreads();
    }

    // direct C write (C/D layout: row = quad*4+r, col = l16)
#pragma unroll
    for (int i = 0; i < 4; ++i)
#pragma unroll
        for (int j = 0; j < 4; ++j) {
            float* Cp = C + (size_t)(m0 + mw * 64 + i * 16 + quad * 4) * OUT_F
                          + (n0 + nw * 64 + j * 16 + l16);
#pragma unroll
            for (int r = 0; r < 4; ++r) Cp[(size_t)r * OUT_F] = acc[i][j][r];
        }
}

// ---------------------------------------------------------------------------
extern "C" void kernel_launch(void* const* d_in, const int* in_sizes, int n_in,
                              void* d_out, int out_size, void* d_ws, size_t ws_size,
                              hipStream_t stream) {
    const float* x  = (const float*)d_in[0];
    const float* s1 = (const float*)d_in[1];
    const float* s2 = (const float*)d_in[2];
    const float* mw = (const float*)d_in[3];
    float* out = (float*)d_out;

    char* ws = (char*)d_ws;
    float* Bpf = (float*)ws;                                          // 16 MB
    unsigned short* Bb = (unsigned short*)(ws + ((size_t)16 << 20));  // 8 MB

    k_perm<<<2048, 256, 0, stream>>>(mw, Bpf);
    k_fold<<<1024, 256, 0, stream>>>(s1, s2, Bpf, Bb);
    k_gemm<<<dim3(128, 16), 256, 0, stream>>>(x, Bb, out);
}

// Round 6
// 399.090 us; speedup vs baseline: 1.2295x; 1.2295x over previous
//
#include <hip/hip_runtime.h>
#include <stdint.h>

#define IN_F 2048
#define OUT_F 2048
#define MTOK 16384   // 4 * 4096 tokens

typedef __attribute__((ext_vector_type(8))) __bf16 bf16x8;
typedef __attribute__((ext_vector_type(4))) float f32x4;
typedef __attribute__((ext_vector_type(4))) unsigned short us4;

typedef const __attribute__((address_space(1))) void g_void;
typedef __attribute__((address_space(3))) void l_void;

// 16B async global->LDS (wave-uniform LDS base + lane*16; swizzle on global src)
__device__ __forceinline__ void async16(void* lds, const void* g) {
    __builtin_amdgcn_global_load_lds((g_void*)(uintptr_t)g, (l_void*)(uintptr_t)lds, 16, 0, 0);
}

// fp32 -> bf16 round-to-nearest-even (bit-identical across all uses)
__device__ __forceinline__ unsigned short f2bf(float x) {
    union { float f; uint32_t u; } v; v.f = x;
    uint32_t r = v.u + 0x7fffu + ((v.u >> 16) & 1u);
    return (unsigned short)(r >> 16);
}

// ---------------------------------------------------------------------------
// K_perm: Bpf[o][i] = MW[o][((i&31)<<6)|(i>>5)]  (shuffle folded into columns,
// fp32, exact). One MW row per block; coalesced read -> padded LDS ->
// permuted read (2-way banks, free) -> coalesced write. ~32 MB traffic.
// ---------------------------------------------------------------------------
__global__ __launch_bounds__(256) void k_perm(
    const float* __restrict__ MW, float* __restrict__ Bpf) {
    __shared__ float buf[2112];   // 2048 + pad every 32
    const int t = threadIdx.x;
    const float* src = MW + (size_t)blockIdx.x * 2048;
    float* dst = Bpf + (size_t)blockIdx.x * 2048;
#pragma unroll
    for (int q = 0; q < 2; ++q) {
        int id4 = q * 256 + t;
        float4 v = *(const float4*)(src + id4 * 4);
        int i = id4 * 4;
        int b = i + (i >> 5);
        buf[b] = v.x; buf[b + 1] = v.y; buf[b + 2] = v.z; buf[b + 3] = v.w;
    }
    __syncthreads();
#pragma unroll
    for (int q = 0; q < 8; ++q) {
        int j = q * 256 + t;
        int i = ((j & 31) << 6) | (j >> 5);
        dst[j] = buf[i + (i >> 5)];
    }
}

// ---------------------------------------------------------------------------
// K_fold: exact fp32 weight fold (butterfly = one linear map):
//   M1[o][g*64+c]   = sum_d W1[g][c][d] * Bp[o][g*64+d]
//   B2[g2*64+d2][i] = sum_c2 W2[g2][c2][d2] * M1[g2*64+c2][i]
// Bp tile read COALESCED from pre-permuted Bpf (R3's strided MW gather was
// ~8x over-fetch + latency-bound). Compute identical to R3 (verified):
// per-lane k-stagger on both inner loops, W2 untransposed.
// ---------------------------------------------------------------------------
#define FP 68   // padded fp32 row: 272B, 16B-aligned

__global__ __launch_bounds__(256) void k_fold(
    const float* __restrict__ s1, const float* __restrict__ s2,
    const float* __restrict__ Bpf, unsigned short* __restrict__ Bb) {
    __shared__ float B0[64 * FP];   // W1[c][d]  -> later M1t[c][o]
    __shared__ float B1[64 * FP];   // Bp[o][d]  -> later W2[c2][d2] (as loaded)
    const int t = threadIdx.x;
    const int g  = blockIdx.x & 31;
    const int rt = blockIdx.x >> 5;
    const int l = t & 15, h = t >> 4;    // h in [0,16)

    // B0[c][d] = stage1[g*64+c][d]  (coalesced float4)
#pragma unroll
    for (int q = 0; q < 4; ++q) {
        int id = q * 256 + t;            // [0,1024)
        int c = id >> 4, d4 = id & 15;
        *(float4*)&B0[c * FP + d4 * 4] =
            *(const float4*)(s1 + (size_t)(g * 64 + c) * 64 + d4 * 4);
    }
    // B1[o][d] = Bpf[rt*64+o][g*64+d]  (coalesced float4, each elem read once)
#pragma unroll
    for (int q = 0; q < 4; ++q) {
        int id = q * 256 + t;            // [0,1024)
        int o = id >> 4, d4 = id & 15;
        *(float4*)&B1[o * FP + d4 * 4] =
            *(const float4*)(Bpf + (size_t)(rt * 64 + o) * 2048 + g * 64 + d4 * 4);
    }
    __syncthreads();

    // step 3: M1t[c][o] = sum_d Bp[o][d] * W1[c][d]; thread owns c=4l..+3, o=4h..+3
    float acc[4][4];
#pragma unroll
    for (int i = 0; i < 4; ++i)
#pragma unroll
        for (int j = 0; j < 4; ++j) acc[i][j] = 0.f;
    {
        const int co = l * 4, oo = h * 4;
#pragma unroll
        for (int dc = 0; dc < 16; ++dc) {
            const int dce = (dc + l) & 15;           // lane k-stagger
            float4 bv[4], wv[4];
#pragma unroll
            for (int i = 0; i < 4; ++i) bv[i] = *(const float4*)&B1[(oo + i) * FP + dce * 4];
#pragma unroll
            for (int j = 0; j < 4; ++j) wv[j] = *(const float4*)&B0[(co + j) * FP + dce * 4];
#pragma unroll
            for (int i = 0; i < 4; ++i)
#pragma unroll
                for (int j = 0; j < 4; ++j)
                    acc[i][j] += bv[i].x * wv[j].x + bv[i].y * wv[j].y
                               + bv[i].z * wv[j].z + bv[i].w * wv[j].w;
        }
    }
    __syncthreads();   // all reads of B0(W1)/B1(Bp) done

    // write M1t[c][o] into B0 (float4 along o); load W2 into B1 as-is
    {
        const int co = l * 4, oo = h * 4;
#pragma unroll
        for (int j = 0; j < 4; ++j) {
            float4 v; v.x = acc[0][j]; v.y = acc[1][j]; v.z = acc[2][j]; v.w = acc[3][j];
            *(float4*)&B0[(co + j) * FP + oo] = v;
        }
    }
#pragma unroll
    for (int q = 0; q < 4; ++q) {
        int id = q * 256 + t;            // [0,1024)
        int c2 = id >> 4, d4 = id & 15;
        *(float4*)&B1[c2 * FP + d4 * 4] =
            *(const float4*)(s2 + (size_t)(rt * 64 + c2) * 64 + d4 * 4);
    }
    __syncthreads();

    // step 5: B2[d2][c] = sum_o W2[o][d2] * M1t[c][o]; thread owns d2=4l..+3, c=4h..+3
    {
        const int d2o = l * 4, cco = h * 4;
#pragma unroll
        for (int i = 0; i < 4; ++i)
#pragma unroll
            for (int j = 0; j < 4; ++j) acc[i][j] = 0.f;
#pragma unroll
        for (int kc = 0; kc < 16; ++kc) {
            const int kce = (kc + l) & 15;           // lane k-stagger
            float4 wv4[4], mv[4];
#pragma unroll
            for (int s = 0; s < 4; ++s) wv4[s] = *(const float4*)&B1[(kce * 4 + s) * FP + d2o];
#pragma unroll
            for (int j = 0; j < 4; ++j) mv[j] = *(const float4*)&B0[(cco + j) * FP + kce * 4];
#pragma unroll
            for (int i = 0; i < 4; ++i)
#pragma unroll
                for (int j = 0; j < 4; ++j)
                    acc[i][j] += wv4[0][i] * mv[j].x + wv4[1][i] * mv[j].y
                               + wv4[2][i] * mv[j].z + wv4[3][i] * mv[j].w;
        }
#pragma unroll
        for (int i = 0; i < 4; ++i) {
            us4 o;
            o[0] = f2bf(acc[i][0]); o[1] = f2bf(acc[i][1]);
            o[2] = f2bf(acc[i][2]); o[3] = f2bf(acc[i][3]);
            *(us4*)(Bb + (size_t)(rt * 64 + d2o + i) * 2048 + g * 64 + cco) = o;
        }
    }
}

// ---------------------------------------------------------------------------
// K_convert: X fp32 -> bf16. Pure stream, NO LDS (full occupancy).
// R5 lesson: fusing this into the gemm's A-staging exposes a per-K-step
// reg round-trip latency + VALU chain that 2 waves/SIMD can't hide.
// Standalone it's a clean ~200 MB stream.
// ---------------------------------------------------------------------------
__global__ __launch_bounds__(256) void k_convert(
    const float* __restrict__ X, unsigned short* __restrict__ Xb) {
    const int gid = blockIdx.x * 256 + threadIdx.x;
    const float4* src = (const float4*)X;
    us4* dst = (us4*)Xb;
#pragma unroll
    for (int k = 0; k < 16; ++k) {
        int idx = k * (2048 * 256) + gid;
        float4 v = src[idx];
        us4 o;
        o[0] = f2bf(v.x); o[1] = f2bf(v.y); o[2] = f2bf(v.z); o[3] = f2bf(v.w);
        dst[idx] = o;
    }
}

// ---------------------------------------------------------------------------
// K1: the single GEMM — EXACT R3 kernel (measured 141.5 us, MfmaUtil 45%,
// FETCH 214 MB, 0 bank conflicts). C[m][o2] = sum_i Xb[m][i] * Bb[o2][i].
// async global->LDS both sides, pre-swizzled source, XOR-swizzled reads,
// bijective chunked XCD remap + temporal m-strip remap.
// ---------------------------------------------------------------------------
__global__ __launch_bounds__(256, 2) void k_gemm(
    const unsigned short* __restrict__ A, const unsigned short* __restrict__ B,
    float* __restrict__ C) {
    __shared__ unsigned short smem[16384];   // As 16KB | Bs 16KB
    unsigned short* As = smem;
    unsigned short* Bs = smem + 8192;
    const int t = threadIdx.x;
    const int lane = t & 63, wave = t >> 6;
    const int quad = lane >> 4, l16 = lane & 15;
    const int mw = wave & 1, nw = wave >> 1;
    const int orig = blockIdx.y * 128 + blockIdx.x;
    const int lin = (orig & 7) * 256 + (orig >> 3);   // chunked XCD swizzle
    const int m0 = (lin >> 4) * 128;
    const int n0 = (lin & 15) * 128;
    const int rr = t >> 3, chunk = t & 7;      // 32 rows x 8 16B-chunks per issue
    const int gsw = (chunk ^ (rr & 7)) * 8;    // swizzled source chunk (shorts)
    const int lsw = l16 & 7;                   // read-side swizzle key

    f32x4 acc[4][4];
#pragma unroll
    for (int i = 0; i < 4; ++i)
#pragma unroll
        for (int j = 0; j < 4; ++j) acc[i][j] = (f32x4)0.f;

    for (int kb = 0; kb < IN_F; kb += 64) {
#pragma unroll
        for (int q = 0; q < 4; ++q) {
            int r = q * 32 + rr;
            async16((char*)As + (size_t)(q * 4096 + t * 16),
                    A + (size_t)(m0 + r) * IN_F + kb + gsw);
            async16((char*)Bs + (size_t)(q * 4096 + t * 16),
                    B + (size_t)(n0 + r) * IN_F + kb + gsw);
        }
        __syncthreads();
#pragma unroll
        for (int ks = 0; ks < 2; ++ks) {
            bf16x8 af[4], bfr[4];
#pragma unroll
            for (int i = 0; i < 4; ++i)
                af[i] = *(const bf16x8*)(As + (mw * 64 + i * 16 + l16) * 64
                                            + (((ks * 4 + quad) ^ lsw) * 8));
#pragma unroll
            for (int j = 0; j < 4; ++j)
                bfr[j] = *(const bf16x8*)(Bs + (nw * 64 + j * 16 + l16) * 64
                                             + (((ks * 4 + quad) ^ lsw) * 8));
#pragma unroll
            for (int i = 0; i < 4; ++i)
#pragma unroll
                for (int j = 0; j < 4; ++j)
                    acc[i][j] = __builtin_amdgcn_mfma_f32_16x16x32_bf16(af[i], bfr[j], acc[i][j], 0, 0, 0);
        }
        __syncthreads();
    }

    // direct C write (C/D layout: row = quad*4+r, col = l16)
#pragma unroll
    for (int i = 0; i < 4; ++i)
#pragma unroll
        for (int j = 0; j < 4; ++j) {
            float* Cp = C + (size_t)(m0 + mw * 64 + i * 16 + quad * 4) * OUT_F
                          + (n0 + nw * 64 + j * 16 + l16);
#pragma unroll
            for (int r = 0; r < 4; ++r) Cp[(size_t)r * OUT_F] = acc[i][j][r];
        }
}

// ---------------------------------------------------------------------------
// Workspace (72 MB, proven footprint): Bpf aliases the first 16 MB of Xb —
// k_fold consumes Bpf before k_convert overwrites it (stream-ordered).
// ---------------------------------------------------------------------------
extern "C" void kernel_launch(void* const* d_in, const int* in_sizes, int n_in,
                              void* d_out, int out_size, void* d_ws, size_t ws_size,
                              hipStream_t stream) {
    const float* x  = (const float*)d_in[0];
    const float* s1 = (const float*)d_in[1];
    const float* s2 = (const float*)d_in[2];
    const float* mw = (const float*)d_in[3];
    float* out = (float*)d_out;

    char* ws = (char*)d_ws;
    unsigned short* Xb  = (unsigned short*)ws;                             // 64 MB
    float*          Bpf = (float*)ws;                                      // 16 MB (aliases Xb head)
    unsigned short* Bb  = (unsigned short*)(ws + (size_t)MTOK * IN_F * 2); // 8 MB @ +64MB

    k_perm<<<2048, 256, 0, stream>>>(mw, Bpf);
    k_fold<<<1024, 256, 0, stream>>>(s1, s2, Bpf, Bb);
    k_convert<<<2048, 256, 0, stream>>>(x, Xb);
    k_gemm<<<dim3(128, 16), 256, 0, stream>>>(Xb, Bb, out);
}

// Round 7
// 381.318 us; speedup vs baseline: 1.2868x; 1.0466x over previous
//
#include <hip/hip_runtime.h>
#include <stdint.h>

#define IN_F 2048
#define OUT_F 2048
#define MTOK 16384   // 4 * 4096 tokens

typedef __attribute__((ext_vector_type(8))) __bf16 bf16x8;
typedef __attribute__((ext_vector_type(4))) float f32x4;
typedef __attribute__((ext_vector_type(4))) unsigned short us4;

typedef const __attribute__((address_space(1))) void g_void;
typedef __attribute__((address_space(3))) void l_void;

// 16B async global->LDS (wave-uniform LDS base + lane*16; swizzle on global src)
__device__ __forceinline__ void async16(void* lds, const void* g) {
    __builtin_amdgcn_global_load_lds((g_void*)(uintptr_t)g, (l_void*)(uintptr_t)lds, 16, 0, 0);
}

// fp32 -> bf16 round-to-nearest-even (bit-identical across all uses)
__device__ __forceinline__ unsigned short f2bf(float x) {
    union { float f; uint32_t u; } v; v.f = x;
    uint32_t r = v.u + 0x7fffu + ((v.u >> 16) & 1u);
    return (unsigned short)(r >> 16);
}

// ---------------------------------------------------------------------------
// K_perm: Bpf[o][i] = MW[o][((i&31)<<6)|(i>>5)]  (shuffle folded into columns,
// fp32, exact). Proven R6.
// ---------------------------------------------------------------------------
__global__ __launch_bounds__(256) void k_perm(
    const float* __restrict__ MW, float* __restrict__ Bpf) {
    __shared__ float buf[2112];   // 2048 + pad every 32
    const int t = threadIdx.x;
    const float* src = MW + (size_t)blockIdx.x * 2048;
    float* dst = Bpf + (size_t)blockIdx.x * 2048;
#pragma unroll
    for (int q = 0; q < 2; ++q) {
        int id4 = q * 256 + t;
        float4 v = *(const float4*)(src + id4 * 4);
        int i = id4 * 4;
        int b = i + (i >> 5);
        buf[b] = v.x; buf[b + 1] = v.y; buf[b + 2] = v.z; buf[b + 3] = v.w;
    }
    __syncthreads();
#pragma unroll
    for (int q = 0; q < 8; ++q) {
        int j = q * 256 + t;
        int i = ((j & 31) << 6) | (j >> 5);
        dst[j] = buf[i + (i >> 5)];
    }
}

// ---------------------------------------------------------------------------
// K_fold: exact fp32 weight fold (butterfly = one linear map). Proven R6.
//   M1[o][g*64+c]   = sum_d W1[g][c][d] * Bp[o][g*64+d]
//   B2[g2*64+d2][i] = sum_c2 W2[g2][c2][d2] * M1[g2*64+c2][i]
// ---------------------------------------------------------------------------
#define FP 68   // padded fp32 row: 272B, 16B-aligned

__global__ __launch_bounds__(256) void k_fold(
    const float* __restrict__ s1, const float* __restrict__ s2,
    const float* __restrict__ Bpf, unsigned short* __restrict__ Bb) {
    __shared__ float B0[64 * FP];   // W1[c][d]  -> later M1t[c][o]
    __shared__ float B1[64 * FP];   // Bp[o][d]  -> later W2[c2][d2] (as loaded)
    const int t = threadIdx.x;
    const int g  = blockIdx.x & 31;
    const int rt = blockIdx.x >> 5;
    const int l = t & 15, h = t >> 4;    // h in [0,16)

#pragma unroll
    for (int q = 0; q < 4; ++q) {
        int id = q * 256 + t;
        int c = id >> 4, d4 = id & 15;
        *(float4*)&B0[c * FP + d4 * 4] =
            *(const float4*)(s1 + (size_t)(g * 64 + c) * 64 + d4 * 4);
    }
#pragma unroll
    for (int q = 0; q < 4; ++q) {
        int id = q * 256 + t;
        int o = id >> 4, d4 = id & 15;
        *(float4*)&B1[o * FP + d4 * 4] =
            *(const float4*)(Bpf + (size_t)(rt * 64 + o) * 2048 + g * 64 + d4 * 4);
    }
    __syncthreads();

    float acc[4][4];
#pragma unroll
    for (int i = 0; i < 4; ++i)
#pragma unroll
        for (int j = 0; j < 4; ++j) acc[i][j] = 0.f;
    {
        const int co = l * 4, oo = h * 4;
#pragma unroll
        for (int dc = 0; dc < 16; ++dc) {
            const int dce = (dc + l) & 15;           // lane k-stagger
            float4 bv[4], wv[4];
#pragma unroll
            for (int i = 0; i < 4; ++i) bv[i] = *(const float4*)&B1[(oo + i) * FP + dce * 4];
#pragma unroll
            for (int j = 0; j < 4; ++j) wv[j] = *(const float4*)&B0[(co + j) * FP + dce * 4];
#pragma unroll
            for (int i = 0; i < 4; ++i)
#pragma unroll
                for (int j = 0; j < 4; ++j)
                    acc[i][j] += bv[i].x * wv[j].x + bv[i].y * wv[j].y
                               + bv[i].z * wv[j].z + bv[i].w * wv[j].w;
        }
    }
    __syncthreads();

    {
        const int co = l * 4, oo = h * 4;
#pragma unroll
        for (int j = 0; j < 4; ++j) {
            float4 v; v.x = acc[0][j]; v.y = acc[1][j]; v.z = acc[2][j]; v.w = acc[3][j];
            *(float4*)&B0[(co + j) * FP + oo] = v;
        }
    }
#pragma unroll
    for (int q = 0; q < 4; ++q) {
        int id = q * 256 + t;
        int c2 = id >> 4, d4 = id & 15;
        *(float4*)&B1[c2 * FP + d4 * 4] =
            *(const float4*)(s2 + (size_t)(rt * 64 + c2) * 64 + d4 * 4);
    }
    __syncthreads();

    {
        const int d2o = l * 4, cco = h * 4;
#pragma unroll
        for (int i = 0; i < 4; ++i)
#pragma unroll
            for (int j = 0; j < 4; ++j) acc[i][j] = 0.f;
#pragma unroll
        for (int kc = 0; kc < 16; ++kc) {
            const int kce = (kc + l) & 15;           // lane k-stagger
            float4 wv4[4], mv[4];
#pragma unroll
            for (int s = 0; s < 4; ++s) wv4[s] = *(const float4*)&B1[(kce * 4 + s) * FP + d2o];
#pragma unroll
            for (int j = 0; j < 4; ++j) mv[j] = *(const float4*)&B0[(cco + j) * FP + kce * 4];
#pragma unroll
            for (int i = 0; i < 4; ++i)
#pragma unroll
                for (int j = 0; j < 4; ++j)
                    acc[i][j] += wv4[0][i] * mv[j].x + wv4[1][i] * mv[j].y
                               + wv4[2][i] * mv[j].z + wv4[3][i] * mv[j].w;
        }
#pragma unroll
        for (int i = 0; i < 4; ++i) {
            us4 o;
            o[0] = f2bf(acc[i][0]); o[1] = f2bf(acc[i][1]);
            o[2] = f2bf(acc[i][2]); o[3] = f2bf(acc[i][3]);
            *(us4*)(Bb + (size_t)(rt * 64 + d2o + i) * 2048 + g * 64 + cco) = o;
        }
    }
}

// ---------------------------------------------------------------------------
// K_convert: X fp32 -> bf16. Pure stream, NO LDS. Proven R6.
// ---------------------------------------------------------------------------
__global__ __launch_bounds__(256) void k_convert(
    const float* __restrict__ X, unsigned short* __restrict__ Xb) {
    const int gid = blockIdx.x * 256 + threadIdx.x;
    const float4* src = (const float4*)X;
    us4* dst = (us4*)Xb;
#pragma unroll
    for (int k = 0; k < 16; ++k) {
        int idx = k * (2048 * 256) + gid;
        float4 v = src[idx];
        us4 o;
        o[0] = f2bf(v.x); o[1] = f2bf(v.y); o[2] = f2bf(v.z); o[3] = f2bf(v.w);
        dst[idx] = o;
    }
}

// ---------------------------------------------------------------------------
// K1: 256x256 GEMM, BK=64, 512 threads (8 waves, 2Mx4N), double-buffered
// 128KB LDS, guide's minimum-2-phase T3 recipe:
//   STAGE(next -> buf^1) ; ds_read(cur) ; setprio(1) MFMA setprio(0) ;
//   __syncthreads  (compiler emits the vmcnt/lgkm drain -> next tile ready)
// One barrier per K-tile (vs 2 per 64-K at 128 tile), 512 MFMA/block-K-tile
// against 8 staged loads/thread. LDS invariant is the PROVEN one:
// LDS[row][c] = global chunk c ^ (row&7); read chunk = kc ^ (l16&7).
// Invariants: (I1) STAGE(t+1 -> buf 1-c) overwrites tile t-1's buffer, whose
// readers all passed iter t-1's barrier. (I2) iter t reads tile t staged in
// iter t-1, drained by iter t-1's __syncthreads (own vmcnt0 + barrier).
// XCD-chunked block remap: 512 blocks = 8 XCDs x 64; 8 n-blocks share an
// A m-strip within one XCD's L2.
// ---------------------------------------------------------------------------
__global__ __launch_bounds__(512, 2) void k_gemm(
    const unsigned short* __restrict__ A, const unsigned short* __restrict__ B,
    float* __restrict__ C) {
    __shared__ unsigned short smem[65536];   // 128 KB: A[2]x32KB | B[2]x32KB
    char* lds = (char*)smem;
    const int t = threadIdx.x;                 // 0..511
    const int lane = t & 63;
    const int wave = t >> 6;                   // 0..7
    const int quad = lane >> 4, l16 = lane & 15;
    const int wm = wave & 1, wn = wave >> 1;   // 2 x 4 wave grid
    const int orig = blockIdx.x;
    const int lin = (orig & 7) * 64 + (orig >> 3);   // bijective XCD chunk (512%8==0)
    const int m0 = (lin >> 3) * 256;
    const int n0 = (lin & 7) * 256;
    const int rr = t >> 3, chunk = t & 7;      // 64 rows x 8 16B-chunks per q-step
    const int gsw = (chunk ^ (rr & 7)) * 8;    // swizzled source chunk (shorts)
    const int lsw = l16 & 7;                   // read-side swizzle key

    f32x4 acc[8][4];
#pragma unroll
    for (int i = 0; i < 8; ++i)
#pragma unroll
        for (int j = 0; j < 4; ++j) acc[i][j] = (f32x4)0.f;

    // ---- prologue: stage K-tile 0 into buf0 ----
#pragma unroll
    for (int q = 0; q < 4; ++q)
        async16(lds + q * 8192 + t * 16,
                A + (size_t)(m0 + q * 64 + rr) * IN_F + 0 + gsw);
#pragma unroll
    for (int q = 0; q < 4; ++q)
        async16(lds + 65536 + q * 8192 + t * 16,
                B + (size_t)(n0 + q * 64 + rr) * IN_F + 0 + gsw);
    __syncthreads();

    for (int kt = 0; kt < 32; ++kt) {
        const int c = kt & 1;
        const unsigned short* As = (const unsigned short*)(lds + c * 32768);
        const unsigned short* Bs = (const unsigned short*)(lds + 65536 + c * 32768);
        char* An = lds + (c ^ 1) * 32768;
        char* Bn = lds + 65536 + (c ^ 1) * 32768;
        const int kbn = (kt + 1) * 64;

        // stage next A-halves (overlaps with ks=0 reads+MFMA)
        if (kt < 31) {
#pragma unroll
            for (int q = 0; q < 4; ++q)
                async16(An + q * 8192 + t * 16,
                        A + (size_t)(m0 + q * 64 + rr) * IN_F + kbn + gsw);
        }
#pragma unroll
        for (int ks = 0; ks < 2; ++ks) {
            if (ks == 1 && kt < 31) {
#pragma unroll
                for (int q = 0; q < 4; ++q)
                    async16(Bn + q * 8192 + t * 16,
                            B + (size_t)(n0 + q * 64 + rr) * IN_F + kbn + gsw);
            }
            bf16x8 af[8], bfr[4];
#pragma unroll
            for (int i = 0; i < 8; ++i)
                af[i] = *(const bf16x8*)(As + (wm * 128 + i * 16 + l16) * 64
                                            + (((ks * 4 + quad) ^ lsw) * 8));
#pragma unroll
            for (int j = 0; j < 4; ++j)
                bfr[j] = *(const bf16x8*)(Bs + (wn * 64 + j * 16 + l16) * 64
                                             + (((ks * 4 + quad) ^ lsw) * 8));
            __builtin_amdgcn_s_setprio(1);
#pragma unroll
            for (int i = 0; i < 8; ++i)
#pragma unroll
                for (int j = 0; j < 4; ++j)
                    acc[i][j] = __builtin_amdgcn_mfma_f32_16x16x32_bf16(af[i], bfr[j], acc[i][j], 0, 0, 0);
            __builtin_amdgcn_s_setprio(0);
        }
        __syncthreads();   // drains own vmcnt (stages landed) + read-complete fence
    }

    // direct C write (C/D layout: row = quad*4+r, col = l16)
#pragma unroll
    for (int i = 0; i < 8; ++i)
#pragma unroll
        for (int j = 0; j < 4; ++j) {
            float* Cp = C + (size_t)(m0 + wm * 128 + i * 16 + quad * 4) * OUT_F
                          + (n0 + wn * 64 + j * 16 + l16);
#pragma unroll
            for (int r = 0; r < 4; ++r) Cp[(size_t)r * OUT_F] = acc[i][j][r];
        }
}

// ---------------------------------------------------------------------------
// Workspace (72 MB): Bpf aliases the first 16 MB of Xb — k_fold consumes Bpf
// before k_convert overwrites it (stream-ordered).
// ---------------------------------------------------------------------------
extern "C" void kernel_launch(void* const* d_in, const int* in_sizes, int n_in,
                              void* d_out, int out_size, void* d_ws, size_t ws_size,
                              hipStream_t stream) {
    const float* x  = (const float*)d_in[0];
    const float* s1 = (const float*)d_in[1];
    const float* s2 = (const float*)d_in[2];
    const float* mw = (const float*)d_in[3];
    float* out = (float*)d_out;

    char* ws = (char*)d_ws;
    unsigned short* Xb  = (unsigned short*)ws;                             // 64 MB
    float*          Bpf = (float*)ws;                                      // 16 MB (aliases Xb head)
    unsigned short* Bb  = (unsigned short*)(ws + (size_t)MTOK * IN_F * 2); // 8 MB @ +64MB

    k_perm<<<2048, 256, 0, stream>>>(mw, Bpf);
    k_fold<<<1024, 256, 0, stream>>>(s1, s2, Bpf, Bb);
    k_convert<<<2048, 256, 0, stream>>>(x, Xb);
    k_gemm<<<512, 512, 0, stream>>>(Xb, Bb, out);
}